// Round 9
// baseline (269.842 us; speedup 1.0000x reference)
//
#include <hip/hip_runtime.h>

#define BATCH 262144
#define TILES_PER_WAVE 4

typedef __attribute__((ext_vector_type(8))) short short8;
typedef __attribute__((ext_vector_type(4))) float f32x4;

static __device__ __forceinline__ unsigned cvtpk(float lo, float hi) {
    unsigned r;
    asm("v_cvt_pk_bf16_f32 %0, %1, %2" : "=v"(r) : "v"(lo), "v"(hi));
    return r;
}
// float -> bf16 bits (RNE) for the weight-prep kernel
static __device__ __forceinline__ unsigned short f2b(float f) {
    unsigned u = __float_as_uint(f);
    return (unsigned short)((u + 0x7fffu + ((u >> 16) & 1u)) >> 16);
}
static __device__ __forceinline__ float b2f(short s) {
    return __uint_as_float(((unsigned)(unsigned short)s) << 16);
}
static __device__ __forceinline__ float sigm(float x) { return 1.0f / (1.0f + __expf(-x)); }
static __device__ __forceinline__ float tanh_f(float x) { return 1.0f - 2.0f / (__expf(2.0f * x) + 1.0f); }

// Per-wave LDS + intra-wave lgkmcnt ordering; raw s_barrier phase-locks waves
// (no vmcnt drain, keeps weight prefetch alive). Uniform loop count -> all
// waves execute the same barrier sequence.
#define STAGE_SYNC() do { \
    asm volatile("s_waitcnt lgkmcnt(0)" ::: "memory"); \
    __builtin_amdgcn_s_barrier(); \
} while (0)

// bf16 weights in workspace: [0:8192) w1, [8192:12288) w2, [12288:24576) w_ih,
//                            [24576:36864) w_hh, [36864:45056) lp_w1
__global__ void prep_weights(const float* __restrict__ w1, const float* __restrict__ w2,
                             const float* __restrict__ wih, const float* __restrict__ whh,
                             const float* __restrict__ lw1, unsigned short* __restrict__ wsb) {
    int i = blockIdx.x * 256 + threadIdx.x;
    float v;
    if (i < 8192) v = w1[i];
    else if (i < 12288) v = w2[i - 8192];
    else if (i < 24576) v = wih[i - 12288];
    else if (i < 36864) v = whh[i - 24576];
    else if (i < 45056) v = lw1[i - 36864];
    else return;
    wsb[i] = f2b(v);
}

#define LDB 72    // bf16 LDS row stride: 144 B rows (16B-aligned rows)
#define LDC 136   // comb row stride: 272 B rows

// (256,4): 128 regs/wave incl. AGPR — R4/R6 proved lower spills, R5 proved
// higher halves occupancy for no gain.
__global__ __launch_bounds__(256, 4) void tgn_kernel(
    const int* __restrict__ pairs, const float* __restrict__ memory,
    const unsigned short* __restrict__ wsb,
    const float* __restrict__ b1, const float* __restrict__ b2,
    const float* __restrict__ bih, const float* __restrict__ bhh,
    const float* __restrict__ lb1, const float* __restrict__ lw2,
    const float* __restrict__ lb2, float* __restrict__ out)
{
    __shared__ __align__(16) short nmem[4][2][16 * LDB];  // 18432 B: n1/n2 bf16
    __shared__ __align__(16) short scr[4][2304];          // 18432 B: h1b@0, msgb@1152; comb overlays

    const int tid = threadIdx.x;
    const int w  = tid >> 6;
    const int l  = tid & 63;
    const int lr = l & 15;       // M/N index within fragment
    const int lg = l >> 4;       // k-group / row-group

    short* n1b  = &nmem[w][0][0];
    short* n2b  = &nmem[w][1][0];
    short* h1b  = &scr[w][0];
    short* msgb = &scr[w][1152];
    short* comb = &scr[w][0];

    const unsigned short* w1b  = wsb;          // [64][128]
    const unsigned short* w2b  = wsb + 8192;   // [64][64]
    const unsigned short* wihb = wsb + 12288;  // [192][64]
    const unsigned short* whhb = wsb + 24576;  // [192][64]
    const unsigned short* lw1b = wsb + 36864;  // [64][128]

    const f32x4 z4 = {0.0f, 0.0f, 0.0f, 0.0f};

    const int tile0 = (blockIdx.x * 4 + w) * TILES_PER_WAVE;

    // prologue: pairs for tile 0 (each lane-group lg owns rows rr*4+lg)
    int i1c[4], i2c[4];
#pragma unroll
    for (int rr = 0; rr < 4; ++rr) {
        int row = tile0 * 16 + rr * 4 + lg;
        i1c[rr] = pairs[row * 2 + 0];
        i2c[rr] = pairs[row * 2 + 1];
    }

#pragma unroll 1   // runtime loop: keep ONE body copy -> I$ and L1 stay warm
    for (int t = 0; t < TILES_PER_WAVE; ++t) {
        const int r0 = (tile0 + t) * 16;

        // ---- stage 0: coalesced gather -> bf16 LDS (16 lanes per 256B row) ----
#pragma unroll
        for (int rr = 0; rr < 4; ++rr) {
            int row = rr * 4 + lg;
            f32x4 v1 = *(const f32x4*)(memory + (long)i1c[rr] * 64 + lr * 4);
            f32x4 v2 = *(const f32x4*)(memory + (long)i2c[rr] * 64 + lr * 4);
            uint2 c1, c2;
            c1.x = cvtpk(v1[0], v1[1]); c1.y = cvtpk(v1[2], v1[3]);
            c2.x = cvtpk(v2[0], v2[1]); c2.y = cvtpk(v2[2], v2[3]);
            *(uint2*)(n1b + row * LDB + lr * 4) = c1;
            *(uint2*)(n2b + row * LDB + lr * 4) = c2;
        }

        // prefetch pairs for next tile (clamped on last iter; latency hidden
        // under stages 1-6 of this tile)
        {
            int tn = (t + 1 < TILES_PER_WAVE) ? t + 1 : t;
#pragma unroll
            for (int rr = 0; rr < 4; ++rr) {
                int row = (tile0 + tn) * 16 + rr * 4 + lg;
                i1c[rr] = pairs[row * 2 + 0];
                i2c[rr] = pairs[row * 2 + 1];
            }
        }
        STAGE_SYNC();

        // ---- stage 1: H1 = relu(X @ w1^T + b1), X = [n1|n2] (16x128) ----
        f32x4 acc[4];
#pragma unroll
        for (int nt = 0; nt < 4; ++nt) acc[nt] = z4;
#pragma unroll
        for (int kt = 0; kt < 4; ++kt) {
            const short* ap = (kt < 2 ? n1b : n2b) + lr * LDB + (kt & 1) * 32 + lg * 8;
            short8 a = *(const short8*)ap;
#pragma unroll
            for (int nt = 0; nt < 4; ++nt) {
                short8 b = *(const short8*)(w1b + (nt * 16 + lr) * 128 + kt * 32 + lg * 8);
                acc[nt] = __builtin_amdgcn_mfma_f32_16x16x32_bf16(a, b, acc[nt], 0, 0, 0);
            }
        }
#pragma unroll
        for (int nt = 0; nt < 4; ++nt) {
            float bv = b1[nt * 16 + lr];
            unsigned p01 = cvtpk(fmaxf(acc[nt][0] + bv, 0.0f), fmaxf(acc[nt][1] + bv, 0.0f));
            unsigned p23 = cvtpk(fmaxf(acc[nt][2] + bv, 0.0f), fmaxf(acc[nt][3] + bv, 0.0f));
            int cb = nt * 16 + lr;
            h1b[(lg * 4 + 0) * LDB + cb] = (short)p01;
            h1b[(lg * 4 + 1) * LDB + cb] = (short)(p01 >> 16);
            h1b[(lg * 4 + 2) * LDB + cb] = (short)p23;
            h1b[(lg * 4 + 3) * LDB + cb] = (short)(p23 >> 16);
        }
        STAGE_SYNC();

        // ---- stage 2: MSG = H1 @ w2^T + b2 (16x64) ----
#pragma unroll
        for (int nt = 0; nt < 4; ++nt) acc[nt] = z4;
#pragma unroll
        for (int kt = 0; kt < 2; ++kt) {
            short8 a = *(const short8*)(h1b + lr * LDB + kt * 32 + lg * 8);
#pragma unroll
            for (int nt = 0; nt < 4; ++nt) {
                short8 b = *(const short8*)(w2b + (nt * 16 + lr) * 64 + kt * 32 + lg * 8);
                acc[nt] = __builtin_amdgcn_mfma_f32_16x16x32_bf16(a, b, acc[nt], 0, 0, 0);
            }
        }
#pragma unroll
        for (int nt = 0; nt < 4; ++nt) {
            float bv = b2[nt * 16 + lr];
            unsigned p01 = cvtpk(acc[nt][0] + bv, acc[nt][1] + bv);
            unsigned p23 = cvtpk(acc[nt][2] + bv, acc[nt][3] + bv);
            int cb = nt * 16 + lr;
            msgb[(lg * 4 + 0) * LDB + cb] = (short)p01;
            msgb[(lg * 4 + 1) * LDB + cb] = (short)(p01 >> 16);
            msgb[(lg * 4 + 2) * LDB + cb] = (short)p23;
            msgb[(lg * 4 + 3) * LDB + cb] = (short)(p23 >> 16);
        }
        STAGE_SYNC();

        // ---- stage 3+4 fused: per column-block nt, 9 gate tiles then GRU ----
        short8 am[2], a1[2], a2[2];
#pragma unroll
        for (int kt = 0; kt < 2; ++kt) {
            am[kt] = *(const short8*)(msgb + lr * LDB + kt * 32 + lg * 8);
            a1[kt] = *(const short8*)(n1b + lr * LDB + kt * 32 + lg * 8);
            a2[kt] = *(const short8*)(n2b + lr * LDB + kt * 32 + lg * 8);
        }
#pragma unroll
        for (int nt = 0; nt < 4; ++nt) {
            f32x4 gir = z4, giz = z4, gin = z4;
            f32x4 g1r = z4, g1z = z4, g1n = z4;
            f32x4 g2r = z4, g2z = z4, g2n = z4;
#pragma unroll
            for (int kt = 0; kt < 2; ++kt) {
                int ko = kt * 32 + lg * 8;
                short8 bir = *(const short8*)(wihb + ((0 + nt) * 16 + lr) * 64 + ko);
                short8 biz = *(const short8*)(wihb + ((4 + nt) * 16 + lr) * 64 + ko);
                short8 bin = *(const short8*)(wihb + ((8 + nt) * 16 + lr) * 64 + ko);
                short8 bhr = *(const short8*)(whhb + ((0 + nt) * 16 + lr) * 64 + ko);
                short8 bhz = *(const short8*)(whhb + ((4 + nt) * 16 + lr) * 64 + ko);
                short8 bhn = *(const short8*)(whhb + ((8 + nt) * 16 + lr) * 64 + ko);
                gir = __builtin_amdgcn_mfma_f32_16x16x32_bf16(am[kt], bir, gir, 0, 0, 0);
                giz = __builtin_amdgcn_mfma_f32_16x16x32_bf16(am[kt], biz, giz, 0, 0, 0);
                gin = __builtin_amdgcn_mfma_f32_16x16x32_bf16(am[kt], bin, gin, 0, 0, 0);
                g1r = __builtin_amdgcn_mfma_f32_16x16x32_bf16(a1[kt], bhr, g1r, 0, 0, 0);
                g1z = __builtin_amdgcn_mfma_f32_16x16x32_bf16(a1[kt], bhz, g1z, 0, 0, 0);
                g1n = __builtin_amdgcn_mfma_f32_16x16x32_bf16(a1[kt], bhn, g1n, 0, 0, 0);
                g2r = __builtin_amdgcn_mfma_f32_16x16x32_bf16(a2[kt], bhr, g2r, 0, 0, 0);
                g2z = __builtin_amdgcn_mfma_f32_16x16x32_bf16(a2[kt], bhz, g2z, 0, 0, 0);
                g2n = __builtin_amdgcn_mfma_f32_16x16x32_bf16(a2[kt], bhn, g2n, 0, 0, 0);
            }
            int j = nt * 16 + lr;
            float bir_ = bih[j], biz_ = bih[64 + j], bin_ = bih[128 + j];
            float bhr_ = bhh[j], bhz_ = bhh[64 + j], bhn_ = bhh[128 + j];
            float o1[4], o2[4];
#pragma unroll
            for (int r = 0; r < 4; ++r) {
                int row = lg * 4 + r;
                float i_r = gir[r] + bir_;
                float i_z = giz[r] + biz_;
                float i_n = gin[r] + bin_;
                // node 1 (h from LDS bf16 copy — no global re-read)
                float rg = sigm(i_r + g1r[r] + bhr_);
                float zg = sigm(i_z + g1z[r] + bhz_);
                float ng = tanh_f(i_n + rg * (g1n[r] + bhn_));
                float h  = b2f(n1b[row * LDB + j]);
                o1[r] = (1.0f - zg) * ng + zg * h;
                // node 2
                rg = sigm(i_r + g2r[r] + bhr_);
                zg = sigm(i_z + g2z[r] + bhz_);
                ng = tanh_f(i_n + rg * (g2n[r] + bhn_));
                h  = b2f(n2b[row * LDB + j]);
                o2[r] = (1.0f - zg) * ng + zg * h;
            }
            unsigned q01 = cvtpk(o1[0], o1[1]), q23 = cvtpk(o1[2], o1[3]);
            unsigned s01 = cvtpk(o2[0], o2[1]), s23 = cvtpk(o2[2], o2[3]);
            comb[(lg * 4 + 0) * LDC + j] = (short)q01;
            comb[(lg * 4 + 1) * LDC + j] = (short)(q01 >> 16);
            comb[(lg * 4 + 2) * LDC + j] = (short)q23;
            comb[(lg * 4 + 3) * LDC + j] = (short)(q23 >> 16);
            comb[(lg * 4 + 0) * LDC + 64 + j] = (short)s01;
            comb[(lg * 4 + 1) * LDC + 64 + j] = (short)(s01 >> 16);
            comb[(lg * 4 + 2) * LDC + 64 + j] = (short)s23;
            comb[(lg * 4 + 3) * LDC + 64 + j] = (short)(s23 >> 16);
        }
        STAGE_SYNC();

        // ---- stage 5: H = relu(COMB @ lp_w1^T + lb1) (16x64) ----
        f32x4 acc5[4];
#pragma unroll
        for (int nt = 0; nt < 4; ++nt) acc5[nt] = z4;
#pragma unroll
        for (int kt = 0; kt < 4; ++kt) {
            short8 a = *(const short8*)(comb + lr * LDC + kt * 32 + lg * 8);
#pragma unroll
            for (int nt = 0; nt < 4; ++nt) {
                short8 b = *(const short8*)(lw1b + (nt * 16 + lr) * 128 + kt * 32 + lg * 8);
                acc5[nt] = __builtin_amdgcn_mfma_f32_16x16x32_bf16(a, b, acc5[nt], 0, 0, 0);
            }
        }

        // ---- stage 6: out = sigmoid(H @ lp_w2^T + lb2), reduce over 64 cols ----
        float part[4] = {0.0f, 0.0f, 0.0f, 0.0f};
#pragma unroll
        for (int nt = 0; nt < 4; ++nt) {
            float w2v = lw2[nt * 16 + lr];
            float bv  = lb1[nt * 16 + lr];
#pragma unroll
            for (int r = 0; r < 4; ++r)
                part[r] += fmaxf(acc5[nt][r] + bv, 0.0f) * w2v;
        }
        float lb2v = lb2[0];
#pragma unroll
        for (int r = 0; r < 4; ++r) {
            float p = part[r];
            p += __shfl_xor(p, 1);
            p += __shfl_xor(p, 2);
            p += __shfl_xor(p, 4);
            p += __shfl_xor(p, 8);
            if (lr == 0) out[r0 + lg * 4 + r] = sigm(p + lb2v);
        }
        // next iter overwrites n1b/n2b: safe — DS ops complete in order per wave,
        // and STAGE_SYNC above ordered all reads of this tile's buffers.
        STAGE_SYNC();
    }
}

extern "C" void kernel_launch(void* const* d_in, const int* in_sizes, int n_in,
                              void* d_out, int out_size, void* d_ws, size_t ws_size,
                              hipStream_t stream) {
    const int*   pairs  = (const int*)d_in[0];
    const float* memory = (const float*)d_in[1];
    const float* w1  = (const float*)d_in[2];
    const float* b1  = (const float*)d_in[3];
    const float* w2  = (const float*)d_in[4];
    const float* b2  = (const float*)d_in[5];
    const float* wih = (const float*)d_in[6];
    const float* whh = (const float*)d_in[7];
    const float* bih = (const float*)d_in[8];
    const float* bhh = (const float*)d_in[9];
    const float* lw1 = (const float*)d_in[10];
    const float* lb1 = (const float*)d_in[11];
    const float* lw2 = (const float*)d_in[12];
    const float* lb2 = (const float*)d_in[13];
    unsigned short* wsb = (unsigned short*)d_ws;

    prep_weights<<<176, 256, 0, stream>>>(w1, w2, wih, whh, lw1, wsb);
    tgn_kernel<<<BATCH / 64 / TILES_PER_WAVE, 256, 0, stream>>>(
        pairs, memory, wsb, b1, b2, bih, bhh, lb1, lw2, lb2, (float*)d_out);
}

// Round 10
// 137.543 us; speedup vs baseline: 1.9619x; 1.9619x over previous
//
#include <hip/hip_runtime.h>

#define BATCH 262144

typedef __attribute__((ext_vector_type(8))) short short8;
typedef __attribute__((ext_vector_type(4))) float f32x4;

static __device__ __forceinline__ unsigned cvtpk(float lo, float hi) {
    unsigned r;
    asm("v_cvt_pk_bf16_f32 %0, %1, %2" : "=v"(r) : "v"(lo), "v"(hi));
    return r;
}
// float -> bf16 bits (RNE) for the weight-prep kernel
static __device__ __forceinline__ unsigned short f2b(float f) {
    unsigned u = __float_as_uint(f);
    return (unsigned short)((u + 0x7fffu + ((u >> 16) & 1u)) >> 16);
}
static __device__ __forceinline__ float b2f(short s) {
    return __uint_as_float(((unsigned)(unsigned short)s) << 16);
}
static __device__ __forceinline__ float sigm(float x) { return 1.0f / (1.0f + __expf(-x)); }
static __device__ __forceinline__ float tanh_f(float x) { return 1.0f - 2.0f / (__expf(2.0f * x) + 1.0f); }

// Working LDS is per-wave; weight LDS is read-only after the one __syncthreads.
// lgkmcnt(0) orders intra-wave ds ops; s_barrier phase-locks waves (no vmcnt drain).
#define STAGE_SYNC() do { \
    asm volatile("s_waitcnt lgkmcnt(0)" ::: "memory"); \
    __builtin_amdgcn_s_barrier(); \
} while (0)

// XOR swizzle on 16B slots within a row: row-major tiles with 128B/256B row
// stride are 16-way bank conflicted on 16-row fragment reads; XOR bits 4..6 of
// the byte offset with (row&7) -> <=2-way aliasing (free). (R4-validated.)
static __device__ __forceinline__ int sw128(int row, int cb) { return row * 128 + (cb ^ ((row & 7) << 4)); }
static __device__ __forceinline__ int sw256(int row, int cb) { return row * 256 + (cb ^ ((row & 7) << 4)); }

// bf16 weights flat in workspace: [0:8192) w1, [8192:12288) w2, [12288:24576) w_ih,
//                                 [24576:36864) w_hh, [36864:45056) lp_w1
__global__ void prep_weights(const float* __restrict__ w1, const float* __restrict__ w2,
                             const float* __restrict__ wih, const float* __restrict__ whh,
                             const float* __restrict__ lw1, unsigned short* __restrict__ wsb) {
    int i = blockIdx.x * 256 + threadIdx.x;
    float v;
    if (i < 8192) v = w1[i];
    else if (i < 12288) v = w2[i - 8192];
    else if (i < 24576) v = wih[i - 12288];
    else if (i < 36864) v = whh[i - 24576];
    else if (i < 45056) v = lw1[i - 36864];
    else return;
    wsb[i] = f2b(v);
}

// Weight LDS byte offsets (tables swizzled at staging time with the same XOR):
//   w1  @ 0      [64][128]  stride 256B
//   w2  @ 16384  [64][64]   stride 128B
//   wih @ 24576  [192][64]  stride 128B
//   whh @ 49152  [192][64]  stride 128B
//   lw1 @ 73728  [64][128]  stride 256B
#define WLDS_BYTES 90112
#define NCHUNK (WLDS_BYTES / 16)

// 512 threads = 8 waves; LDS 155648 B -> 1 block/CU (LDS-pinned), so registers
// are free: no launch-bounds cap (R4/R6/R9: forced caps => scratch spills).
__global__ __launch_bounds__(512) void tgn_kernel(
    const int* __restrict__ pairs, const float* __restrict__ memory,
    const unsigned short* __restrict__ wsb,
    const float* __restrict__ b1, const float* __restrict__ b2,
    const float* __restrict__ bih, const float* __restrict__ bhh,
    const float* __restrict__ lb1, const float* __restrict__ lw2,
    const float* __restrict__ lb2, float* __restrict__ out)
{
    __shared__ __align__(16) char wlds[WLDS_BYTES];   // 90112 B shared weights
    __shared__ __align__(16) char work[8][8192];      // 65536 B: per-wave {n1,n2,scr}

    const int tid = threadIdx.x;
    const int w  = tid >> 6;
    const int l  = tid & 63;
    const int lr = l & 15;       // M/N index within fragment
    const int lg = l >> 4;       // k-group / row-group

    // ---- stage weights: global (flat) -> LDS (swizzled), 16B chunks ----
    for (int c = tid; c < NCHUNK; c += 512) {
        int byte = c * 16;
        int base, sh;
        if (byte < 16384)      { base = 0;     sh = 8; }   // w1, 256B rows
        else if (byte < 24576) { base = 16384; sh = 7; }   // w2, 128B rows
        else if (byte < 49152) { base = 24576; sh = 7; }   // wih
        else if (byte < 73728) { base = 49152; sh = 7; }   // whh
        else                   { base = 73728; sh = 8; }   // lw1
        int t   = byte - base;
        int row = t >> sh;
        int dst = base + (t ^ ((row & 7) << 4));
        *(short8*)(wlds + dst) = *(const short8*)((const char*)wsb + byte);
    }
    __syncthreads();   // full barrier incl. vmcnt/lgkm drain: weights now visible

    char* n1b  = &work[w][0];     // [16][64] bf16, sw128
    char* n2b  = &work[w][2048];
    char* h1b  = &work[w][4096];  // [16][64] bf16, sw128
    char* msgb = &work[w][6144];
    char* comb = &work[w][4096];  // [16][128] bf16, sw256 (overlays h1+msg)

    const char* w1l  = wlds + 0;
    const char* w2l  = wlds + 16384;
    const char* wihl = wlds + 24576;
    const char* whhl = wlds + 49152;
    const char* lw1l = wlds + 73728;

    const f32x4 z4 = {0.0f, 0.0f, 0.0f, 0.0f};
    const int r0 = (blockIdx.x * 8 + w) * 16;

    // ---- stage 0: coalesced gather -> bf16 LDS (16 lanes per 256B row) ----
#pragma unroll
    for (int rr = 0; rr < 4; ++rr) {
        int row = rr * 4 + lg;
        long i1 = pairs[(r0 + row) * 2 + 0];
        long i2 = pairs[(r0 + row) * 2 + 1];
        f32x4 v1 = *(const f32x4*)(memory + i1 * 64 + lr * 4);
        f32x4 v2 = *(const f32x4*)(memory + i2 * 64 + lr * 4);
        uint2 c1, c2;
        c1.x = cvtpk(v1[0], v1[1]); c1.y = cvtpk(v1[2], v1[3]);
        c2.x = cvtpk(v2[0], v2[1]); c2.y = cvtpk(v2[2], v2[3]);
        int off = sw128(row, lr * 8);
        *(uint2*)(n1b + off) = c1;
        *(uint2*)(n2b + off) = c2;
    }
    STAGE_SYNC();

    // ---- stage 1: H1 = relu(X @ w1^T + b1), X = [n1|n2] (16x128) ----
    f32x4 acc[4];
#pragma unroll
    for (int nt = 0; nt < 4; ++nt) acc[nt] = z4;
#pragma unroll
    for (int kt = 0; kt < 4; ++kt) {
        const char* base = (kt < 2) ? n1b : n2b;
        short8 a = *(const short8*)(base + sw128(lr, (kt & 1) * 64 + lg * 16));
#pragma unroll
        for (int nt = 0; nt < 4; ++nt) {
            short8 b = *(const short8*)(w1l + sw256(nt * 16 + lr, kt * 64 + lg * 16));
            acc[nt] = __builtin_amdgcn_mfma_f32_16x16x32_bf16(a, b, acc[nt], 0, 0, 0);
        }
    }
#pragma unroll
    for (int nt = 0; nt < 4; ++nt) {
        float bv = b1[nt * 16 + lr];
        unsigned p01 = cvtpk(fmaxf(acc[nt][0] + bv, 0.0f), fmaxf(acc[nt][1] + bv, 0.0f));
        unsigned p23 = cvtpk(fmaxf(acc[nt][2] + bv, 0.0f), fmaxf(acc[nt][3] + bv, 0.0f));
        int cb = nt * 32 + lr * 2;
        *(short*)(h1b + sw128(lg * 4 + 0, cb)) = (short)p01;
        *(short*)(h1b + sw128(lg * 4 + 1, cb)) = (short)(p01 >> 16);
        *(short*)(h1b + sw128(lg * 4 + 2, cb)) = (short)p23;
        *(short*)(h1b + sw128(lg * 4 + 3, cb)) = (short)(p23 >> 16);
    }
    STAGE_SYNC();

    // ---- stage 2: MSG = H1 @ w2^T + b2 (16x64) ----
#pragma unroll
    for (int nt = 0; nt < 4; ++nt) acc[nt] = z4;
#pragma unroll
    for (int kt = 0; kt < 2; ++kt) {
        short8 a = *(const short8*)(h1b + sw128(lr, kt * 64 + lg * 16));
#pragma unroll
        for (int nt = 0; nt < 4; ++nt) {
            short8 b = *(const short8*)(w2l + sw128(nt * 16 + lr, kt * 64 + lg * 16));
            acc[nt] = __builtin_amdgcn_mfma_f32_16x16x32_bf16(a, b, acc[nt], 0, 0, 0);
        }
    }
#pragma unroll
    for (int nt = 0; nt < 4; ++nt) {
        float bv = b2[nt * 16 + lr];
        unsigned p01 = cvtpk(acc[nt][0] + bv, acc[nt][1] + bv);
        unsigned p23 = cvtpk(acc[nt][2] + bv, acc[nt][3] + bv);
        int cb = nt * 32 + lr * 2;
        *(short*)(msgb + sw128(lg * 4 + 0, cb)) = (short)p01;
        *(short*)(msgb + sw128(lg * 4 + 1, cb)) = (short)(p01 >> 16);
        *(short*)(msgb + sw128(lg * 4 + 2, cb)) = (short)p23;
        *(short*)(msgb + sw128(lg * 4 + 3, cb)) = (short)(p23 >> 16);
    }
    STAGE_SYNC();

    // ---- stage 3+4 fused: per column-block nt, 9 gate tiles then GRU ----
    short8 am[2], a1[2], a2[2];
#pragma unroll
    for (int kt = 0; kt < 2; ++kt) {
        am[kt] = *(const short8*)(msgb + sw128(lr, kt * 64 + lg * 16));
        a1[kt] = *(const short8*)(n1b + sw128(lr, kt * 64 + lg * 16));
        a2[kt] = *(const short8*)(n2b + sw128(lr, kt * 64 + lg * 16));
    }
#pragma unroll
    for (int nt = 0; nt < 4; ++nt) {
        f32x4 gir = z4, giz = z4, gin = z4;
        f32x4 g1r = z4, g1z = z4, g1n = z4;
        f32x4 g2r = z4, g2z = z4, g2n = z4;
#pragma unroll
        for (int kt = 0; kt < 2; ++kt) {
            int ko = kt * 64 + lg * 16;
            short8 bir = *(const short8*)(wihl + sw128((0 + nt) * 16 + lr, ko));
            short8 biz = *(const short8*)(wihl + sw128((4 + nt) * 16 + lr, ko));
            short8 bin = *(const short8*)(wihl + sw128((8 + nt) * 16 + lr, ko));
            short8 bhr = *(const short8*)(whhl + sw128((0 + nt) * 16 + lr, ko));
            short8 bhz = *(const short8*)(whhl + sw128((4 + nt) * 16 + lr, ko));
            short8 bhn = *(const short8*)(whhl + sw128((8 + nt) * 16 + lr, ko));
            gir = __builtin_amdgcn_mfma_f32_16x16x32_bf16(am[kt], bir, gir, 0, 0, 0);
            giz = __builtin_amdgcn_mfma_f32_16x16x32_bf16(am[kt], biz, giz, 0, 0, 0);
            gin = __builtin_amdgcn_mfma_f32_16x16x32_bf16(am[kt], bin, gin, 0, 0, 0);
            g1r = __builtin_amdgcn_mfma_f32_16x16x32_bf16(a1[kt], bhr, g1r, 0, 0, 0);
            g1z = __builtin_amdgcn_mfma_f32_16x16x32_bf16(a1[kt], bhz, g1z, 0, 0, 0);
            g1n = __builtin_amdgcn_mfma_f32_16x16x32_bf16(a1[kt], bhn, g1n, 0, 0, 0);
            g2r = __builtin_amdgcn_mfma_f32_16x16x32_bf16(a2[kt], bhr, g2r, 0, 0, 0);
            g2z = __builtin_amdgcn_mfma_f32_16x16x32_bf16(a2[kt], bhz, g2z, 0, 0, 0);
            g2n = __builtin_amdgcn_mfma_f32_16x16x32_bf16(a2[kt], bhn, g2n, 0, 0, 0);
        }
        int j = nt * 16 + lr;
        float bir_ = bih[j], biz_ = bih[64 + j], bin_ = bih[128 + j];
        float bhr_ = bhh[j], bhz_ = bhh[64 + j], bhn_ = bhh[128 + j];
        float o1[4], o2[4];
#pragma unroll
        for (int r = 0; r < 4; ++r) {
            int row = lg * 4 + r;
            float i_r = gir[r] + bir_;
            float i_z = giz[r] + biz_;
            float i_n = gin[r] + bin_;
            float rg = sigm(i_r + g1r[r] + bhr_);
            float zg = sigm(i_z + g1z[r] + bhz_);
            float ng = tanh_f(i_n + rg * (g1n[r] + bhn_));
            float h  = b2f(*(const short*)(n1b + sw128(row, j * 2)));
            o1[r] = (1.0f - zg) * ng + zg * h;
            rg = sigm(i_r + g2r[r] + bhr_);
            zg = sigm(i_z + g2z[r] + bhz_);
            ng = tanh_f(i_n + rg * (g2n[r] + bhn_));
            h  = b2f(*(const short*)(n2b + sw128(row, j * 2)));
            o2[r] = (1.0f - zg) * ng + zg * h;
        }
        unsigned q01 = cvtpk(o1[0], o1[1]), q23 = cvtpk(o1[2], o1[3]);
        unsigned s01 = cvtpk(o2[0], o2[1]), s23 = cvtpk(o2[2], o2[3]);
        *(short*)(comb + sw256(lg * 4 + 0, j * 2)) = (short)q01;
        *(short*)(comb + sw256(lg * 4 + 1, j * 2)) = (short)(q01 >> 16);
        *(short*)(comb + sw256(lg * 4 + 2, j * 2)) = (short)q23;
        *(short*)(comb + sw256(lg * 4 + 3, j * 2)) = (short)(q23 >> 16);
        *(short*)(comb + sw256(lg * 4 + 0, 128 + j * 2)) = (short)s01;
        *(short*)(comb + sw256(lg * 4 + 1, 128 + j * 2)) = (short)(s01 >> 16);
        *(short*)(comb + sw256(lg * 4 + 2, 128 + j * 2)) = (short)s23;
        *(short*)(comb + sw256(lg * 4 + 3, 128 + j * 2)) = (short)(s23 >> 16);
    }
    STAGE_SYNC();

    // ---- stage 5: H = relu(COMB @ lp_w1^T + lb1) (16x64) ----
    f32x4 acc5[4];
#pragma unroll
    for (int nt = 0; nt < 4; ++nt) acc5[nt] = z4;
#pragma unroll
    for (int kt = 0; kt < 4; ++kt) {
        short8 a = *(const short8*)(comb + sw256(lr, kt * 64 + lg * 16));
#pragma unroll
        for (int nt = 0; nt < 4; ++nt) {
            short8 b = *(const short8*)(lw1l + sw256(nt * 16 + lr, kt * 64 + lg * 16));
            acc5[nt] = __builtin_amdgcn_mfma_f32_16x16x32_bf16(a, b, acc5[nt], 0, 0, 0);
        }
    }

    // ---- stage 6: out = sigmoid(H @ lp_w2^T + lb2), reduce over 64 cols ----
    float part[4] = {0.0f, 0.0f, 0.0f, 0.0f};
#pragma unroll
    for (int nt = 0; nt < 4; ++nt) {
        float w2v = lw2[nt * 16 + lr];
        float bv  = lb1[nt * 16 + lr];
#pragma unroll
        for (int r = 0; r < 4; ++r)
            part[r] += fmaxf(acc5[nt][r] + bv, 0.0f) * w2v;
    }
    float lb2v = lb2[0];
#pragma unroll
    for (int r = 0; r < 4; ++r) {
        float p = part[r];
        p += __shfl_xor(p, 1);
        p += __shfl_xor(p, 2);
        p += __shfl_xor(p, 4);
        p += __shfl_xor(p, 8);
        if (lr == 0) out[r0 + lg * 4 + r] = sigm(p + lb2v);
    }
}

extern "C" void kernel_launch(void* const* d_in, const int* in_sizes, int n_in,
                              void* d_out, int out_size, void* d_ws, size_t ws_size,
                              hipStream_t stream) {
    const int*   pairs  = (const int*)d_in[0];
    const float* memory = (const float*)d_in[1];
    const float* w1  = (const float*)d_in[2];
    const float* b1  = (const float*)d_in[3];
    const float* w2  = (const float*)d_in[4];
    const float* b2  = (const float*)d_in[5];
    const float* wih = (const float*)d_in[6];
    const float* whh = (const float*)d_in[7];
    const float* bih = (const float*)d_in[8];
    const float* bhh = (const float*)d_in[9];
    const float* lw1 = (const float*)d_in[10];
    const float* lb1 = (const float*)d_in[11];
    const float* lw2 = (const float*)d_in[12];
    const float* lb2 = (const float*)d_in[13];
    unsigned short* wsb = (unsigned short*)d_ws;

    prep_weights<<<176, 256, 0, stream>>>(w1, w2, wih, whh, lw1, wsb);
    tgn_kernel<<<BATCH / 128, 512, 0, stream>>>(pairs, memory, wsb, b1, b2, bih, bhh,
                                                lb1, lw2, lb2, (float*)d_out);
}